// Round 8
// baseline (148.905 us; speedup 1.0000x reference)
//
#include <hip/hip_runtime.h>
#include <hip/hip_bf16.h>
#include <math.h>

// Problem constants (B=2, C=256, H=W=64, Co=256, 3x3, stride1, pad1)
#define BB 2
#define CC 256
#define HH 64
#define WW 64
#define COo 256
#define HWs 4096
#define K2 9
#define CK 2304   // C*9

typedef __attribute__((ext_vector_type(4))) float floatx4;
typedef __attribute__((ext_vector_type(8))) short shortx8;   // 8 bf16

// ---- workspace layout (float units) ----
#define O_OFF   0          // final offset  B*18*4096 = 147456 f
#define O_MASK  147456     // final modulator B*9*4096 = 73728 f
#define O_WBF   221184     // reg_w bf16 [co][k*256+c] = 294912 f  (tap-major)
#define O_WPK   516096     // convA weights [g2][kc8][tap9][nf2][lane][8] = 73728 f
#define O_XT    10027008   // x NHWC bf16 [b][y][x][c] = 1048576 f
#define O_RT    11075584   // residual NHWC bf16 = 1048576 f

__device__ __forceinline__ void gll16(const __hip_bfloat16* g, __hip_bfloat16* l) {
    __builtin_amdgcn_global_load_lds(
        (const __attribute__((address_space(1))) unsigned int*)g,
        (__attribute__((address_space(3))) unsigned int*)l, 16, 0, 0);
}

__device__ __forceinline__ short f2bf(float v) {
    __hip_bfloat16 h = __float2bfloat16(v);
    return *reinterpret_cast<short*>(&h);
}

__device__ __forceinline__ float bf2f(short s) {
    unsigned u = ((unsigned)(unsigned short)s) << 16;
    return __builtin_bit_cast(float, u);
}

// ---------------------------------------------------------------------------
// K0: FUSED prep = transpose (blocks 0..2047) + weight pack (blocks 2048+).
// Wbf tap-major: Wbf[co*2304 + k*256 + c] = reg_w[co][c][k]. (verbatim R17)
// ---------------------------------------------------------------------------
__global__ __launch_bounds__(256) void prep_kernel(
    const float* __restrict__ x,
    const float* __restrict__ residual,
    const float* __restrict__ reg_w,
    const float* __restrict__ off_w,
    const float* __restrict__ mod_w,
    __hip_bfloat16* __restrict__ xT,
    __hip_bfloat16* __restrict__ resT,
    __hip_bfloat16* __restrict__ Wbf,
    __hip_bfloat16* __restrict__ Wpk)
{
    int blk = blockIdx.x;
    int t = threadIdx.x;
    if (blk < 2048) {
        int sel = blk >> 10;             // 0 = x, 1 = residual
        int bk  = blk & 1023;            // ((b*64 + y)*8 + oc)
        int oc = bk & 7;
        int y  = (bk >> 3) & 63;
        int b  = bk >> 9;
        int wo = t & 63;
        int cg = t >> 6;
        int c0 = oc * 32 + cg * 8;
        const float* src = (sel ? residual : x)
                           + ((size_t)(b * CC + c0) * HH + y) * WW + wo;
        shortx8 pk;
#pragma unroll
        for (int j = 0; j < 8; ++j) pk[j] = f2bf(src[(size_t)j * HWs]);
        __hip_bfloat16* dst = sel ? resT : xT;
        *(shortx8*)(dst + ((size_t)b * 4096 + y * 64 + wo) * 256 + c0) = pk;
    } else {
        int idx = (blk - 2048) * 256 + t;
        if (idx < CK * COo) {
            // dst (co, k, c) <- reg_w[co*2304 + c*9 + k]
            int co = idx / CK;
            int r  = idx - co * CK;
            int k  = r >> 8;
            int c  = r & 255;
            Wbf[idx] = __float2bfloat16(reg_w[(size_t)co * CK + c * 9 + k]);
        }
        if (idx < 147456) {
            int g    = idx / 73728;
            int rem  = idx % 73728;
            int kc   = rem / 9216;
            int r2   = rem % 9216;
            int tap  = r2 / 1024;
            int r3   = r2 & 1023;
            int nf   = r3 >> 9;
            int r4   = r3 & 511;
            int lane = r4 >> 3;
            int j    = r4 & 7;
            int c    = kc * 32 + (lane >> 4) * 8 + j;
            int n    = nf * 16 + (lane & 15);
            float v = 0.f;
            if (g == 0) { if (n < 18) v = off_w[((size_t)n * CC + c) * 9 + tap]; }
            else        { if (n < 9)  v = mod_w[((size_t)n * CC + c) * 9 + tap]; }
            Wpk[idx] = __float2bfloat16(v);
        }
    }
}

// ---------------------------------------------------------------------------
// K1: DIRECT offset+modulator conv. (verbatim R11/R14/R17)
// ---------------------------------------------------------------------------
__global__ __launch_bounds__(512) void convA2_kernel(
    const __hip_bfloat16* __restrict__ xT,
    const __hip_bfloat16* __restrict__ resT,
    const __hip_bfloat16* __restrict__ Wpk,
    const float* __restrict__ off_b,
    const float* __restrict__ mod_b,
    float* __restrict__ off_out,
    float* __restrict__ mask_out)
{
    int blk = blockIdx.x;
    int tile = blk & 127;
    int g = (blk >> 7) & 1;
    int b = blk >> 8;
    int t = threadIdx.x;
    int lane = t & 63;
    int w = t >> 6;                  // 0..7
    int ph = w & 1;                  // pixel half (16 pixels)
    int ks = w >> 1;                 // K quarter (kc pair)
    int ln = lane & 15;
    int quad = lane >> 4;

    const __hip_bfloat16* src = (g ? xT : resT) + (size_t)b * 4096 * 256;
    const __hip_bfloat16* wg  = Wpk + (size_t)g * 73728 + (size_t)ks * 2 * 9216;

    int pix = tile * 32 + ph * 16 + ln;   // this lane's A-row (pixel)
    int ho = pix >> 6, wo = pix & 63;

    floatx4 acc0 = (floatx4){0.f, 0.f, 0.f, 0.f};
    floatx4 acc1 = (floatx4){0.f, 0.f, 0.f, 0.f};

#pragma unroll
    for (int tap = 0; tap < 9; ++tap) {
        int ky = tap / 3, kx = tap % 3;
        int r  = ho + ky - 1;
        int cx = wo + kx - 1;
        bool v = (r >= 0) && (r < HH) && (cx >= 0) && (cx < WW);
        int hw = v ? (r * WW + cx) : 0;
        const __hip_bfloat16* abase = src + (size_t)hw * 256 + quad * 8 + ks * 64;
        const __hip_bfloat16* wbase = wg + (size_t)tap * 1024 + lane * 8;
#pragma unroll
        for (int kc = 0; kc < 2; ++kc) {
            shortx8 af = *(const shortx8*)(abase + kc * 32);
            if (!v) {
                shortx8 zf = {0,0,0,0,0,0,0,0};
                af = zf;
            }
            shortx8 b0 = *(const shortx8*)(wbase + (size_t)kc * 9216);
            shortx8 b1 = *(const shortx8*)(wbase + (size_t)kc * 9216 + 512);
            acc0 = __builtin_amdgcn_mfma_f32_16x16x32_bf16(af, b0, acc0, 0, 0, 0);
            acc1 = __builtin_amdgcn_mfma_f32_16x16x32_bf16(af, b1, acc1, 0, 0, 0);
        }
    }

    __shared__ float s_red[8][64][8];    // 16 KB
    *(floatx4*)&s_red[w][lane][0] = acc0;
    *(floatx4*)&s_red[w][lane][4] = acc1;
    __syncthreads();
    if (w < 2) {                         // w == ph, ks == 0
#pragma unroll
        for (int j = 0; j < 4; ++j) {
            acc0[j] = s_red[w][lane][j]     + s_red[w + 2][lane][j]
                    + s_red[w + 4][lane][j] + s_red[w + 6][lane][j];
            acc1[j] = s_red[w][lane][4 + j]     + s_red[w + 2][lane][4 + j]
                    + s_red[w + 4][lane][4 + j] + s_red[w + 6][lane][4 + j];
        }

#pragma unroll
        for (int nf = 0; nf < 2; ++nf) {
            floatx4 a = nf ? acc1 : acc0;
            int n = nf * 16 + ln;
#pragma unroll
            for (int i2 = 0; i2 < 4; ++i2) {
                int p = tile * 32 + w * 16 + quad * 4 + i2;
                if (g == 0) {
                    if (n < 18)
                        off_out[((size_t)b * 18 + n) * HWs + p] = a[i2] + off_b[n];
                } else {
                    if (n < 9) {
                        float z = a[i2] + mod_b[n];
                        mask_out[((size_t)b * 9 + n) * HWs + p] =
                            2.f / (1.f + __expf(-z));
                    }
                }
            }
        }
    }
}

// ---------------------------------------------------------------------------
// K2 (R18): FUSED gather+GEMM = R17 skeleton with BM 32->16 for occupancy.
// Grid 1024 (= mt512 x nt2), block 256 = 4 waves (each wave = 16 pix x one
// 32-co quarter of BN=128), LDS ~46 KB -> 3 blocks/CU resident = 3 waves/
// SIMD (was 2). Mechanism = R13's proven lever: more co-resident blocks
// cover the per-step __syncthreads vmcnt(0) drain. BN stays 128 (gather
// redundancy = 256/BN = 2x, unchanged). Same validated skeleton: one
// __syncthreads per K-step, dbuf B-DMA (same 4 gll16/wave pattern), XOR
// swizzles, R17 cross-step gather pipeline, R13 epilogue. Gather now uses
// threads 0..127 (16 pix x 8 ch-groups); waves 2-3 skip it (wave-uniform).
// Accumulation order per output unchanged -> absmax 0.0625.
// ---------------------------------------------------------------------------
__global__ __launch_bounds__(256) void gemm_fused_kernel(
    const __hip_bfloat16* __restrict__ xT,
    const float* __restrict__ off,
    const float* __restrict__ mask,
    const __hip_bfloat16* __restrict__ Wbf,
    float* __restrict__ out)
{
    int blk0 = blockIdx.x;
    int blk = ((blk0 & 7) << 7) | (blk0 >> 3);   // XCD chunking, bijective on 1024
    int nt = blk & 1;
    int mt = blk >> 1;              // 0..511 (16-pixel tiles)
    int t  = threadIdx.x;
    int lane = t & 63;
    int w    = t >> 6;              // 0..3 = 32-co quarter
    int quad = lane >> 4;
    int ln   = lane & 15;

    __shared__ __hip_bfloat16 As[2][16 * 64];    // 4 KB
    __shared__ __hip_bfloat16 Bs[2][128 * 64];   // 32 KB
    __shared__ int   s_mi[16][K2][4];            // 2.3 KB corner indices
    __shared__ float s_mw[16][K2][4];            // 2.3 KB corner weights (x mask)
    __shared__ float s_out[4][16 * 20];          // 5 KB epilogue
    // total ~46 KB -> 3 blocks/CU

    int b = mt >> 8;
    const __hip_bfloat16* xb = xT + (size_t)b * 4096 * 256;

    int lr8 = lane >> 3;            // staging row within 8
    int sub = lane & 7;             // 16B slot
    int chk = sub ^ lr8;            // pre-swizzled global k-chunk

    const __hip_bfloat16* gB = Wbf + (size_t)(nt * 128 + w * 8 + lr8) * CK + chk * 8;
    int lof = w * 512;

    floatx4 acc[2];
#pragma unroll
    for (int nf = 0; nf < 2; ++nf) acc[nf] = (floatx4){0.f, 0.f, 0.f, 0.f};

    // issue B buf0 DMA first (latency overlaps meta compute)
#pragma unroll
    for (int h = 0; h < 4; ++h)
        gll16(gB + (size_t)(h * 32) * CK, &Bs[0][lof + h * 2048]);

    // ---- meta prologue: corner idx/weights for 16 pixels x 9 taps ----
    for (int u = t; u < 16 * K2; u += 256) {
        int pl_ = u / K2;
        int k  = u - pl_ * K2;
        int pix = mt * 16 + pl_;
        int hw = pix & 4095;
        int ho = hw >> 6, wo = hw & 63;
        float dy = off [(((size_t)b * 18 + 2 * k    ) << 12) + hw];
        float dx = off [(((size_t)b * 18 + 2 * k + 1) << 12) + hw];
        float m  = mask[(((size_t)b * 9  + k        ) << 12) + hw];
        float py = (float)(ho - 1 + k / 3) + dy;
        float px = (float)(wo - 1 + k % 3) + dx;
        float y0f = floorf(py), x0f = floorf(px);
        float wy1 = py - y0f, wx1 = px - x0f;
        float wy0 = 1.f - wy1, wx0 = 1.f - wx1;
        int y0 = (int)y0f, x0 = (int)x0f;
#pragma unroll
        for (int j = 0; j < 4; ++j) {
            int yy = y0 + (j >> 1);
            int xx = x0 + (j & 1);
            float wj = ((j == 0) ? wy0 * wx0 :
                        (j == 1) ? wy0 * wx1 :
                        (j == 2) ? wy1 * wx0 : wy1 * wx1) * m;
            bool valid = (yy >= 0) && (yy < HH) && (xx >= 0) && (xx < WW);
            s_mi[pl_][k][j] = valid ? (yy * WW + xx) : 0;
            s_mw[pl_][k][j] = valid ? wj : 0.f;
        }
    }

    int pl  = (t >> 3) & 15;        // gather pixel (0..15), threads 0..127
    int ch8 = t & 7;                // 8-channel group within 64
    bool gth = (t < 128);           // gather workers = waves 0,1 (wave-uniform)
    int aslot = pl * 64 + ((ch8 ^ (pl & 7)) * 8);   // swizzled As column

    // per-tap meta (for the step currently being LOADED)
    int   mi0, mi1, mi2, mi3;
    float mw0, mw1, mw2, mw3;
    auto meta_load = [&](int k) {
        mi0 = s_mi[pl][k][0]; mi1 = s_mi[pl][k][1];
        mi2 = s_mi[pl][k][2]; mi3 = s_mi[pl][k][3];
        mw0 = s_mw[pl][k][0]; mw1 = s_mw[pl][k][1];
        mw2 = s_mw[pl][k][2]; mw3 = s_mw[pl][k][3];
    };

    // in-flight gather state: loaded corners + their weights (snapshot)
    shortx8 gc0, gc1, gc2, gc3;
    float   gw0, gw1, gw2, gw3;
    auto gather_load = [&](int cb) {
        const __hip_bfloat16* xr = xb + cb * 64 + ch8 * 8;
        gc0 = *(const shortx8*)(xr + (size_t)mi0 * 256);
        gc1 = *(const shortx8*)(xr + (size_t)mi1 * 256);
        gc2 = *(const shortx8*)(xr + (size_t)mi2 * 256);
        gc3 = *(const shortx8*)(xr + (size_t)mi3 * 256);
        gw0 = mw0; gw1 = mw1; gw2 = mw2; gw3 = mw3;
    };
    auto gather_store = [&](int buf) {
        shortx8 o;
#pragma unroll
        for (int j = 0; j < 8; ++j)
            o[j] = f2bf(gw0 * bf2f(gc0[j]) + gw1 * bf2f(gc1[j])
                      + gw2 * bf2f(gc2[j]) + gw3 * bf2f(gc3[j]));
        *(shortx8*)&As[buf][aslot] = o;
    };

    __syncthreads();                // meta visible (also drains B0 DMA)
    if (gth) {
        meta_load(0);
        gather_load(0);             // corners for step 0
        gather_store(0);            // exposed once (prologue only)
        gather_load(1);             // corners for step 1 (cb=1, tap 0)
    }

    int swz = ln & 7;               // read-slot XOR key

    for (int kt = 0; kt < 36; ++kt) {
        int cur = kt & 1;
        int nxt = cur ^ 1;
        __syncthreads();            // buf[cur] staged; ALSO drains gc loads
        if (kt + 1 < 36) {
            int ko = (kt + 1) * 64;
#pragma unroll
            for (int h = 0; h < 4; ++h)
                gll16(gB + (size_t)(h * 32) * CK + ko, &Bs[nxt][lof + h * 2048]);
        }
#pragma unroll
        for (int kh = 0; kh < 2; ++kh) {
            int slot = ((kh * 4 + quad) ^ swz) * 8;
            shortx8 af = *(const shortx8*)
                &As[cur][ln * 64 + slot];
            shortx8 bf[2];
#pragma unroll
            for (int nf = 0; nf < 2; ++nf)
                bf[nf] = *(const shortx8*)
                    &Bs[cur][(w * 32 + nf * 16 + ln) * 64 + slot];
#pragma unroll
            for (int nf = 0; nf < 2; ++nf)
                acc[nf] = __builtin_amdgcn_mfma_f32_16x16x32_bf16(
                    af, bf[nf], acc[nf], 0, 0, 0);
        }
        if (gth && kt + 1 < 36) gather_store(nxt);   // gc drained -> zero-wait
        if (gth && kt + 2 < 36) {                    // issue loads for kt+2
            int k2 = kt + 2;
            if ((k2 & 3) == 0) meta_load(k2 >> 2);
            gather_load(k2 & 3);
        }
    }

    // epilogue (R13-validated pattern): per-wave LDS transpose
    int bb = mt >> 8;
    int hw0 = (mt & 255) * 16;
    float* sw = &s_out[w][0];
    int co_l = lane >> 2;
    int seg  = lane & 3;
#pragma unroll
    for (int nf = 0; nf < 2; ++nf) {
        *(floatx4*)&sw[ln * 20 + quad * 4] = acc[nf];
        floatx4 v0 = *(const floatx4*)&sw[co_l * 20 + seg * 4];
        int co = nt * 128 + w * 32 + nf * 16 + co_l;
        float* orow = out + ((size_t)(bb * COo + co) << 12) + hw0;
        *(floatx4*)&orow[seg * 4] = v0;
    }
}

// ---------------------------------------------------------------------------
extern "C" void kernel_launch(void* const* d_in, const int* in_sizes, int n_in,
                              void* d_out, int out_size, void* d_ws, size_t ws_size,
                              hipStream_t stream)
{
    const float* x     = (const float*)d_in[0];
    const float* resid = (const float*)d_in[1];
    const float* off_w = (const float*)d_in[2];
    const float* off_b = (const float*)d_in[3];
    const float* mod_w = (const float*)d_in[4];
    const float* mod_b = (const float*)d_in[5];
    const float* reg_w = (const float*)d_in[6];
    float* out = (float*)d_out;

    float* ws = (float*)d_ws;
    float* off_buf   = ws + O_OFF;
    float* mask_buf  = ws + O_MASK;
    __hip_bfloat16* Wbf  = (__hip_bfloat16*)(ws + O_WBF);
    __hip_bfloat16* Wpk  = (__hip_bfloat16*)(ws + O_WPK);
    __hip_bfloat16* xT   = (__hip_bfloat16*)(ws + O_XT);
    __hip_bfloat16* resT = (__hip_bfloat16*)(ws + O_RT);

    // fused transpose (2048 blocks) + weight pack (2304 blocks)
    prep_kernel<<<2048 + (CK * COo + 255) / 256, 256, 0, stream>>>(
        x, resid, reg_w, off_w, mod_w, xT, resT, Wbf, Wpk);

    convA2_kernel<<<512, 512, 0, stream>>>(xT, resT, Wpk, off_b, mod_b,
                                           off_buf, mask_buf);

    gemm_fused_kernel<<<1024, 256, 0, stream>>>(xT, off_buf, mask_buf, Wbf, out);
}

// Round 10
// 131.220 us; speedup vs baseline: 1.1348x; 1.1348x over previous
//
#include <hip/hip_runtime.h>
#include <hip/hip_bf16.h>
#include <math.h>

// Problem constants (B=2, C=256, H=W=64, Co=256, 3x3, stride1, pad1)
#define BB 2
#define CC 256
#define HH 64
#define WW 64
#define COo 256
#define HWs 4096
#define K2 9
#define CK 2304   // C*9

typedef __attribute__((ext_vector_type(4))) float floatx4;
typedef __attribute__((ext_vector_type(8))) short shortx8;   // 8 bf16

// ---- workspace layout (float units) ----
#define O_OFF   0          // final offset  B*18*4096 = 147456 f
#define O_MASK  147456     // final modulator B*9*4096 = 73728 f
#define O_WBF   221184     // reg_w bf16 [co][k*256+c] = 294912 f  (tap-major)
#define O_WPK   516096     // convA weights [g2][kc8][tap9][nf2][lane][8] = 73728 f
#define O_XT    10027008   // x NHWC bf16 [b][y][x][c] = 1048576 f
#define O_RT    11075584   // residual NHWC bf16 = 1048576 f

__device__ __forceinline__ void gll16(const __hip_bfloat16* g, __hip_bfloat16* l) {
    __builtin_amdgcn_global_load_lds(
        (const __attribute__((address_space(1))) unsigned int*)g,
        (__attribute__((address_space(3))) unsigned int*)l, 16, 0, 0);
}

__device__ __forceinline__ short f2bf(float v) {
    __hip_bfloat16 h = __float2bfloat16(v);
    return *reinterpret_cast<short*>(&h);
}

__device__ __forceinline__ float bf2f(short s) {
    unsigned u = ((unsigned)(unsigned short)s) << 16;
    return __builtin_bit_cast(float, u);
}

// ---------------------------------------------------------------------------
// K0: FUSED prep = transpose (blocks 0..2047) + weight pack (blocks 2048+).
// Wbf tap-major: Wbf[co*2304 + k*256 + c] = reg_w[co][c][k]. (verbatim R17)
// ---------------------------------------------------------------------------
__global__ __launch_bounds__(256) void prep_kernel(
    const float* __restrict__ x,
    const float* __restrict__ residual,
    const float* __restrict__ reg_w,
    const float* __restrict__ off_w,
    const float* __restrict__ mod_w,
    __hip_bfloat16* __restrict__ xT,
    __hip_bfloat16* __restrict__ resT,
    __hip_bfloat16* __restrict__ Wbf,
    __hip_bfloat16* __restrict__ Wpk)
{
    int blk = blockIdx.x;
    int t = threadIdx.x;
    if (blk < 2048) {
        int sel = blk >> 10;             // 0 = x, 1 = residual
        int bk  = blk & 1023;            // ((b*64 + y)*8 + oc)
        int oc = bk & 7;
        int y  = (bk >> 3) & 63;
        int b  = bk >> 9;
        int wo = t & 63;
        int cg = t >> 6;
        int c0 = oc * 32 + cg * 8;
        const float* src = (sel ? residual : x)
                           + ((size_t)(b * CC + c0) * HH + y) * WW + wo;
        shortx8 pk;
#pragma unroll
        for (int j = 0; j < 8; ++j) pk[j] = f2bf(src[(size_t)j * HWs]);
        __hip_bfloat16* dst = sel ? resT : xT;
        *(shortx8*)(dst + ((size_t)b * 4096 + y * 64 + wo) * 256 + c0) = pk;
    } else {
        int idx = (blk - 2048) * 256 + t;
        if (idx < CK * COo) {
            // dst (co, k, c) <- reg_w[co*2304 + c*9 + k]
            int co = idx / CK;
            int r  = idx - co * CK;
            int k  = r >> 8;
            int c  = r & 255;
            Wbf[idx] = __float2bfloat16(reg_w[(size_t)co * CK + c * 9 + k]);
        }
        if (idx < 147456) {
            int g    = idx / 73728;
            int rem  = idx % 73728;
            int kc   = rem / 9216;
            int r2   = rem % 9216;
            int tap  = r2 / 1024;
            int r3   = r2 & 1023;
            int nf   = r3 >> 9;
            int r4   = r3 & 511;
            int lane = r4 >> 3;
            int j    = r4 & 7;
            int c    = kc * 32 + (lane >> 4) * 8 + j;
            int n    = nf * 16 + (lane & 15);
            float v = 0.f;
            if (g == 0) { if (n < 18) v = off_w[((size_t)n * CC + c) * 9 + tap]; }
            else        { if (n < 9)  v = mod_w[((size_t)n * CC + c) * 9 + tap]; }
            Wpk[idx] = __float2bfloat16(v);
        }
    }
}

// ---------------------------------------------------------------------------
// K1: DIRECT offset+modulator conv. (R11/R14/R17 structure; R20 change:
// g=1 (modulator) only produces n<9, all in acc0 -> the acc1/b1 path is
// dead for g=1 and is skipped under a BLOCK-UNIFORM branch. acc1 stays
// zero; the LDS reduction sums zeros; the n<9 epilogue mask is unchanged.
// This is the ONLY change vs the validated R17 build (isolated attribution).
// ---------------------------------------------------------------------------
__global__ __launch_bounds__(512) void convA2_kernel(
    const __hip_bfloat16* __restrict__ xT,
    const __hip_bfloat16* __restrict__ resT,
    const __hip_bfloat16* __restrict__ Wpk,
    const float* __restrict__ off_b,
    const float* __restrict__ mod_b,
    float* __restrict__ off_out,
    float* __restrict__ mask_out)
{
    int blk = blockIdx.x;
    int tile = blk & 127;
    int g = (blk >> 7) & 1;
    int b = blk >> 8;
    int t = threadIdx.x;
    int lane = t & 63;
    int w = t >> 6;                  // 0..7
    int ph = w & 1;                  // pixel half (16 pixels)
    int ks = w >> 1;                 // K quarter (kc pair)
    int ln = lane & 15;
    int quad = lane >> 4;

    const __hip_bfloat16* src = (g ? xT : resT) + (size_t)b * 4096 * 256;
    const __hip_bfloat16* wg  = Wpk + (size_t)g * 73728 + (size_t)ks * 2 * 9216;

    int pix = tile * 32 + ph * 16 + ln;   // this lane's A-row (pixel)
    int ho = pix >> 6, wo = pix & 63;

    floatx4 acc0 = (floatx4){0.f, 0.f, 0.f, 0.f};
    floatx4 acc1 = (floatx4){0.f, 0.f, 0.f, 0.f};

    if (g == 0) {
        // offset conv: N=32 (18 used), both acc paths
#pragma unroll
        for (int tap = 0; tap < 9; ++tap) {
            int ky = tap / 3, kx = tap % 3;
            int r  = ho + ky - 1;
            int cx = wo + kx - 1;
            bool v = (r >= 0) && (r < HH) && (cx >= 0) && (cx < WW);
            int hw = v ? (r * WW + cx) : 0;
            const __hip_bfloat16* abase = src + (size_t)hw * 256 + quad * 8 + ks * 64;
            const __hip_bfloat16* wbase = wg + (size_t)tap * 1024 + lane * 8;
#pragma unroll
            for (int kc = 0; kc < 2; ++kc) {
                shortx8 af = *(const shortx8*)(abase + kc * 32);
                if (!v) {
                    shortx8 zf = {0,0,0,0,0,0,0,0};
                    af = zf;
                }
                shortx8 b0 = *(const shortx8*)(wbase + (size_t)kc * 9216);
                shortx8 b1 = *(const shortx8*)(wbase + (size_t)kc * 9216 + 512);
                acc0 = __builtin_amdgcn_mfma_f32_16x16x32_bf16(af, b0, acc0, 0, 0, 0);
                acc1 = __builtin_amdgcn_mfma_f32_16x16x32_bf16(af, b1, acc1, 0, 0, 0);
            }
        }
    } else {
        // modulator conv: only n<9 used -> acc0 only (half the MFMAs/B-loads)
#pragma unroll
        for (int tap = 0; tap < 9; ++tap) {
            int ky = tap / 3, kx = tap % 3;
            int r  = ho + ky - 1;
            int cx = wo + kx - 1;
            bool v = (r >= 0) && (r < HH) && (cx >= 0) && (cx < WW);
            int hw = v ? (r * WW + cx) : 0;
            const __hip_bfloat16* abase = src + (size_t)hw * 256 + quad * 8 + ks * 64;
            const __hip_bfloat16* wbase = wg + (size_t)tap * 1024 + lane * 8;
#pragma unroll
            for (int kc = 0; kc < 2; ++kc) {
                shortx8 af = *(const shortx8*)(abase + kc * 32);
                if (!v) {
                    shortx8 zf = {0,0,0,0,0,0,0,0};
                    af = zf;
                }
                shortx8 b0 = *(const shortx8*)(wbase + (size_t)kc * 9216);
                acc0 = __builtin_amdgcn_mfma_f32_16x16x32_bf16(af, b0, acc0, 0, 0, 0);
            }
        }
    }

    __shared__ float s_red[8][64][8];    // 16 KB
    *(floatx4*)&s_red[w][lane][0] = acc0;
    *(floatx4*)&s_red[w][lane][4] = acc1;
    __syncthreads();
    if (w < 2) {                         // w == ph, ks == 0
#pragma unroll
        for (int j = 0; j < 4; ++j) {
            acc0[j] = s_red[w][lane][j]     + s_red[w + 2][lane][j]
                    + s_red[w + 4][lane][j] + s_red[w + 6][lane][j];
            acc1[j] = s_red[w][lane][4 + j]     + s_red[w + 2][lane][4 + j]
                    + s_red[w + 4][lane][4 + j] + s_red[w + 6][lane][4 + j];
        }

#pragma unroll
        for (int nf = 0; nf < 2; ++nf) {
            floatx4 a = nf ? acc1 : acc0;
            int n = nf * 16 + ln;
#pragma unroll
            for (int i2 = 0; i2 < 4; ++i2) {
                int p = tile * 32 + w * 16 + quad * 4 + i2;
                if (g == 0) {
                    if (n < 18)
                        off_out[((size_t)b * 18 + n) * HWs + p] = a[i2] + off_b[n];
                } else {
                    if (n < 9) {
                        float z = a[i2] + mod_b[n];
                        mask_out[((size_t)b * 9 + n) * HWs + p] =
                            2.f / (1.f + __expf(-z));
                    }
                }
            }
        }
    }
}

// ---------------------------------------------------------------------------
// K2 (R17, verbatim — validated 130.6): FUSED gather+GEMM, grid 512 =
// mt256 x nt2, block 256 = 4 waves, 54 KB LDS -> 2 blocks/CU, one
// __syncthreads per K-step, dbuf B-DMA with pre-swizzled global src, XOR
// read swizzle, cross-step (depth-1) gather pipeline, per-wave epilogue.
// (R19's depth-2 E/O pipeline FAILED validation (absmax 0.24) — abandoned;
// sync-structure edits without race-screening have negative EV here.)
// ---------------------------------------------------------------------------
__global__ __launch_bounds__(256) void gemm_fused_kernel(
    const __hip_bfloat16* __restrict__ xT,
    const float* __restrict__ off,
    const float* __restrict__ mask,
    const __hip_bfloat16* __restrict__ Wbf,
    float* __restrict__ out)
{
    int blk0 = blockIdx.x;
    int blk = ((blk0 & 7) << 6) | (blk0 >> 3);   // XCD chunking, bijective on 512
    int nt = blk & 1;
    int mt = blk >> 1;              // 0..255 (32-pixel tiles)
    int t  = threadIdx.x;
    int lane = t & 63;
    int w    = t >> 6;              // 0..3
    int quad = lane >> 4;
    int ln   = lane & 15;
    int wm = w & 1;                 // M half (16 rows)
    int wn = w >> 1;                // N half (64 cols)

    __shared__ __hip_bfloat16 As[2][32 * 64];    // 8 KB
    __shared__ __hip_bfloat16 Bs[2][128 * 64];   // 32 KB
    __shared__ int   s_mi[32][K2][4];            // 4.5 KB corner indices
    __shared__ float s_mw[32][K2][4];            // 4.5 KB corner weights (x mask)
    __shared__ float s_out[4][16 * 20];          // 5 KB epilogue
    // total 54 KB -> 2 blocks/CU

    int b = mt >> 7;
    const __hip_bfloat16* xb = xT + (size_t)b * 4096 * 256;

    int lr8 = lane >> 3;            // staging row within 8
    int sub = lane & 7;             // 16B slot
    int chk = sub ^ lr8;            // pre-swizzled global k-chunk

    const __hip_bfloat16* gB = Wbf + (size_t)(nt * 128 + w * 8 + lr8) * CK + chk * 8;
    int lof = w * 512;

    floatx4 acc[4];
#pragma unroll
    for (int nf = 0; nf < 4; ++nf) acc[nf] = (floatx4){0.f, 0.f, 0.f, 0.f};

    // issue B buf0 DMA first (latency overlaps meta compute)
#pragma unroll
    for (int h = 0; h < 4; ++h)
        gll16(gB + (size_t)(h * 32) * CK, &Bs[0][lof + h * 2048]);

    // ---- meta prologue: corner idx/weights for 32 pixels x 9 taps ----
    for (int u = t; u < 32 * K2; u += 256) {
        int pl_ = u / K2;
        int k  = u - pl_ * K2;
        int pix = mt * 32 + pl_;
        int hw = pix & 4095;
        int ho = hw >> 6, wo = hw & 63;
        float dy = off [(((size_t)b * 18 + 2 * k    ) << 12) + hw];
        float dx = off [(((size_t)b * 18 + 2 * k + 1) << 12) + hw];
        float m  = mask[(((size_t)b * 9  + k        ) << 12) + hw];
        float py = (float)(ho - 1 + k / 3) + dy;
        float px = (float)(wo - 1 + k % 3) + dx;
        float y0f = floorf(py), x0f = floorf(px);
        float wy1 = py - y0f, wx1 = px - x0f;
        float wy0 = 1.f - wy1, wx0 = 1.f - wx1;
        int y0 = (int)y0f, x0 = (int)x0f;
#pragma unroll
        for (int j = 0; j < 4; ++j) {
            int yy = y0 + (j >> 1);
            int xx = x0 + (j & 1);
            float wj = ((j == 0) ? wy0 * wx0 :
                        (j == 1) ? wy0 * wx1 :
                        (j == 2) ? wy1 * wx0 : wy1 * wx1) * m;
            bool valid = (yy >= 0) && (yy < HH) && (xx >= 0) && (xx < WW);
            s_mi[pl_][k][j] = valid ? (yy * WW + xx) : 0;
            s_mw[pl_][k][j] = valid ? wj : 0.f;
        }
    }

    int pl  = t >> 3;               // gather: this thread's pixel (0..31)
    int ch8 = t & 7;                // gather: 8-channel group within 64
    int aslot = pl * 64 + ((ch8 ^ (pl & 7)) * 8);   // swizzled As column

    // per-tap meta (for the step currently being LOADED)
    int   mi0, mi1, mi2, mi3;
    float mw0, mw1, mw2, mw3;
    auto meta_load = [&](int k) {
        mi0 = s_mi[pl][k][0]; mi1 = s_mi[pl][k][1];
        mi2 = s_mi[pl][k][2]; mi3 = s_mi[pl][k][3];
        mw0 = s_mw[pl][k][0]; mw1 = s_mw[pl][k][1];
        mw2 = s_mw[pl][k][2]; mw3 = s_mw[pl][k][3];
    };

    // in-flight gather state: loaded corners + their weights (snapshot)
    shortx8 gc0, gc1, gc2, gc3;
    float   gw0, gw1, gw2, gw3;
    auto gather_load = [&](int cb) {
        const __hip_bfloat16* xr = xb + cb * 64 + ch8 * 8;
        gc0 = *(const shortx8*)(xr + (size_t)mi0 * 256);
        gc1 = *(const shortx8*)(xr + (size_t)mi1 * 256);
        gc2 = *(const shortx8*)(xr + (size_t)mi2 * 256);
        gc3 = *(const shortx8*)(xr + (size_t)mi3 * 256);
        gw0 = mw0; gw1 = mw1; gw2 = mw2; gw3 = mw3;
    };
    auto gather_store = [&](int buf) {
        shortx8 o;
#pragma unroll
        for (int j = 0; j < 8; ++j)
            o[j] = f2bf(gw0 * bf2f(gc0[j]) + gw1 * bf2f(gc1[j])
                      + gw2 * bf2f(gc2[j]) + gw3 * bf2f(gc3[j]));
        *(shortx8*)&As[buf][aslot] = o;
    };

    __syncthreads();                // meta visible (also drains B0 DMA)
    meta_load(0);
    gather_load(0);                 // corners for step 0
    gather_store(0);                // exposed once (prologue only)
    gather_load(1);                 // corners for step 1 (cb=1, tap 0)

    int swz = ln & 7;               // read-slot XOR key

    for (int kt = 0; kt < 36; ++kt) {
        int cur = kt & 1;
        int nxt = cur ^ 1;
        __syncthreads();            // buf[cur] staged; ALSO drains gc loads
        if (kt + 1 < 36) {
            int ko = (kt + 1) * 64;
#pragma unroll
            for (int h = 0; h < 4; ++h)
                gll16(gB + (size_t)(h * 32) * CK + ko, &Bs[nxt][lof + h * 2048]);
        }
#pragma unroll
        for (int kh = 0; kh < 2; ++kh) {
            int slot = ((kh * 4 + quad) ^ swz) * 8;
            shortx8 af = *(const shortx8*)
                &As[cur][(wm * 16 + ln) * 64 + slot];
            shortx8 bf[4];
#pragma unroll
            for (int nf = 0; nf < 4; ++nf)
                bf[nf] = *(const shortx8*)
                    &Bs[cur][(wn * 64 + nf * 16 + ln) * 64 + slot];
#pragma unroll
            for (int nf = 0; nf < 4; ++nf)
                acc[nf] = __builtin_amdgcn_mfma_f32_16x16x32_bf16(
                    af, bf[nf], acc[nf], 0, 0, 0);
        }
        if (kt + 1 < 36) gather_store(nxt);   // gc drained -> zero-wait consume
        if (kt + 2 < 36) {                    // issue loads for step kt+2
            int k2 = kt + 2;
            if ((k2 & 3) == 0) meta_load(k2 >> 2);
            gather_load(k2 & 3);
        }
    }

    // epilogue (verbatim R13/R14): per-wave LDS transpose
    int bb = mt >> 7;
    int hw0 = (mt & 127) * 32 + wm * 16;
    float* sw = &s_out[w][0];
    int co_l = lane >> 2;
    int seg  = lane & 3;
#pragma unroll
    for (int nf = 0; nf < 4; ++nf) {
        *(floatx4*)&sw[ln * 20 + quad * 4] = acc[nf];
        floatx4 v0 = *(const floatx4*)&sw[co_l * 20 + seg * 4];
        int co = nt * 128 + wn * 64 + nf * 16 + co_l;
        float* orow = out + ((size_t)(bb * COo + co) << 12) + hw0;
        *(floatx4*)&orow[seg * 4] = v0;
    }
}

// ---------------------------------------------------------------------------
extern "C" void kernel_launch(void* const* d_in, const int* in_sizes, int n_in,
                              void* d_out, int out_size, void* d_ws, size_t ws_size,
                              hipStream_t stream)
{
    const float* x     = (const float*)d_in[0];
    const float* resid = (const float*)d_in[1];
    const float* off_w = (const float*)d_in[2];
    const float* off_b = (const float*)d_in[3];
    const float* mod_w = (const float*)d_in[4];
    const float* mod_b = (const float*)d_in[5];
    const float* reg_w = (const float*)d_in[6];
    float* out = (float*)d_out;

    float* ws = (float*)d_ws;
    float* off_buf   = ws + O_OFF;
    float* mask_buf  = ws + O_MASK;
    __hip_bfloat16* Wbf  = (__hip_bfloat16*)(ws + O_WBF);
    __hip_bfloat16* Wpk  = (__hip_bfloat16*)(ws + O_WPK);
    __hip_bfloat16* xT   = (__hip_bfloat16*)(ws + O_XT);
    __hip_bfloat16* resT = (__hip_bfloat16*)(ws + O_RT);

    // fused transpose (2048 blocks) + weight pack (2304 blocks)
    prep_kernel<<<2048 + (CK * COo + 255) / 256, 256, 0, stream>>>(
        x, resid, reg_w, off_w, mod_w, xT, resT, Wbf, Wpk);

    convA2_kernel<<<512, 512, 0, stream>>>(xT, resT, Wpk, off_b, mod_b,
                                           off_buf, mask_buf);

    gemm_fused_kernel<<<512, 256, 0, stream>>>(xT, off_buf, mask_buf, Wbf, out);
}